// Round 2
// 394.704 us; speedup vs baseline: 1.0971x; 1.0971x over previous
//
#include <hip/hip_runtime.h>

// SparseGCNConv: out = segment_sum(norm * f[src], dst, N) @ W^T + bias
// R7 (resubmit; prior bench aborted on container-acquire infra failure):
// R6's pipeline with pull_kernel restructured for issue efficiency:
// 16-lane-per-edge dwordx4 gathers (1 VMEM instr = 4 edges' full 256B rows),
// group-broadcast bufB loads, cndmask edge guard (no branch), packed
// v_pk_fma_f32 accumulate, final cross-group shfl_xor reduce.

#define NN    100000
#define NE    3200000
#define D     128
#define NBKT2 1563  // ceil(NN/64); bucket b = dst >> 6
#define NTILE 6250  // NN/16 node tiles (exact)

typedef __attribute__((ext_vector_type(8))) short bf16x8;
typedef __attribute__((ext_vector_type(4))) float f32x4;
typedef __attribute__((ext_vector_type(2))) float f32x2;

static __device__ __forceinline__ unsigned short f2bf(float x) {
  unsigned u = __float_as_uint(x);
  u += 0x7FFFu + ((u >> 16) & 1u);  // RTNE
  return (unsigned short)(u >> 16);
}

// ---------------------------------------------------------------------------
// W [128][128] fp32 -> bf16 in MFMA B-fragment order:
// wfrag[((tc*4+ks)*64 + lane)*8 + j] = bf16(w[c][k])
//   where c = tc*16 + (lane&15), k = ks*32 + (lane>>4)*8 + j.
__global__ __launch_bounds__(256) void cvtw_kernel(
    const float* __restrict__ w, unsigned short* __restrict__ wfrag) {
  const int i = blockIdx.x * 256 + threadIdx.x;  // 16384 elems, 64 blocks
  const int c = i >> 7, k = i & 127;
  const int pos = ((((c >> 4) << 2) + (k >> 5)) * 64 +
                   (((k >> 3) & 3) << 4) + (c & 15)) * 8 + (k & 7);
  wfrag[pos] = f2bf(w[i]);
}

// ---------------------------------------------------------------------------
// MFMA gemm: g[n][c] = sum_k f[n][k] w[c][k], output plain row-major bf16.
// One wave per 16-node tile, all 128 channels (8 ch-tiles x 4 k-steps).
__global__ __launch_bounds__(256) void gemm_kernel(
    const float* __restrict__ f, const unsigned short* __restrict__ wfrag,
    unsigned short* __restrict__ gb) {
  const int wv = blockIdx.x * 4 + (threadIdx.x >> 6);
  if (wv >= NTILE) return;
  const int lane = threadIdx.x & 63;
  const int mrow = lane & 15;
  const int q = lane >> 4;
  const long node = (long)wv * 16 + mrow;
  const float* fr = f + node * D + q * 8;

  bf16x8 a[4];
#pragma unroll
  for (int ks = 0; ks < 4; ++ks) {
    const float4 lo = *(const float4*)(fr + ks * 32);
    const float4 hi = *(const float4*)(fr + ks * 32 + 4);
    union { bf16x8 v; unsigned short u[8]; } pa;
    pa.u[0] = f2bf(lo.x); pa.u[1] = f2bf(lo.y);
    pa.u[2] = f2bf(lo.z); pa.u[3] = f2bf(lo.w);
    pa.u[4] = f2bf(hi.x); pa.u[5] = f2bf(hi.y);
    pa.u[6] = f2bf(hi.z); pa.u[7] = f2bf(hi.w);
    a[ks] = pa.v;
  }

  const long nbase = (long)wv * 16 + (q << 2);
#pragma unroll
  for (int tc = 0; tc < 8; ++tc) {
    f32x4 acc = {0.f, 0.f, 0.f, 0.f};
#pragma unroll
    for (int ks = 0; ks < 4; ++ks) {
      const bf16x8 b =
          *(const bf16x8*)(wfrag + (((tc << 2) + ks) * 64 + lane) * 8);
      acc = __builtin_amdgcn_mfma_f32_16x16x32_bf16(a[ks], b, acc, 0, 0, 0);
    }
    const int c = (tc << 4) + mrow;
#pragma unroll
    for (int r = 0; r < 4; ++r) gb[(nbase + r) * D + c] = f2bf(acc[r]);
  }
}

// ---------------------------------------------------------------------------
// Bucket histogram (1563 counters), LDS-aggregated int atomics.  (proven R5)
__global__ __launch_bounds__(256) void hist_kernel(const int* __restrict__ dst,
                                                   int* __restrict__ gcnt) {
  __shared__ int h[NBKT2];
  const int t = threadIdx.x;
  for (int b = t; b < NBKT2; b += 256) h[b] = 0;
  __syncthreads();
  const int base = blockIdx.x * 4096;
#pragma unroll
  for (int i = 0; i < 16; ++i) {
    int e = base + i * 256 + t;
    if (e < NE) atomicAdd(&h[dst[e] >> 6], 1);
  }
  __syncthreads();
  for (int b = t; b < NBKT2; b += 256)
    if (h[b]) atomicAdd(&gcnt[b], h[b]);
}

// Exclusive scan of 1563 counts.  (proven R5)
__global__ __launch_bounds__(1024) void scan_kernel(const int* __restrict__ gcnt,
                                                    int* __restrict__ bstart,
                                                    int* __restrict__ cur,
                                                    int* __restrict__ row_ptr) {
  __shared__ int s[2048];
  const int t = threadIdx.x;
  s[t] = (t < NBKT2) ? gcnt[t] : 0;
  s[t + 1024] = (t + 1024 < NBKT2) ? gcnt[t + 1024] : 0;
  __syncthreads();
  if (t < 64) {
    int part = 0;
#pragma unroll
    for (int i = 0; i < 32; ++i) part += s[(t << 5) + i];
    int inc = part;
#pragma unroll
    for (int off = 1; off < 64; off <<= 1) {
      int x = __shfl_up(inc, off, 64);
      if (t >= off) inc += x;
    }
    int run = inc - part;
#pragma unroll
    for (int i = 0; i < 32; ++i) {
      int idx = (t << 5) + i;
      int v = s[idx];
      s[idx] = run;
      run += v;
    }
  }
  __syncthreads();
  if (t < NBKT2) { bstart[t] = s[t]; cur[t] = s[t]; }
  if (t + 1024 < NBKT2) { bstart[t + 1024] = s[t + 1024]; cur[t + 1024] = s[t + 1024]; }
  if (t == 0) { bstart[NBKT2] = NE; row_ptr[NN] = NE; }
}

// ---------------------------------------------------------------------------
// Bin edges into buckets (dense runs).  (proven R5)
__global__ __launch_bounds__(512) void bin_kernel(
    const int* __restrict__ src, const int* __restrict__ dst,
    const float* __restrict__ norm, int* __restrict__ cur,
    int2* __restrict__ bufA) {
  __shared__ int bcnt[NBKT2];
  __shared__ int bbase[NBKT2];
  const int t = threadIdx.x;
  for (int b = t; b < NBKT2; b += 512) bcnt[b] = 0;
  __syncthreads();
  const int base = blockIdx.x * 16384;
#pragma unroll
  for (int i = 0; i < 32; ++i) {
    int e = base + i * 512 + t;
    if (e < NE) atomicAdd(&bcnt[dst[e] >> 6], 1);
  }
  __syncthreads();
  for (int b = t; b < NBKT2; b += 512) {
    int c = bcnt[b];
    if (c) bbase[b] = atomicAdd(&cur[b], c);
    bcnt[b] = 0;  // reuse as rank
  }
  __syncthreads();
#pragma unroll
  for (int i = 0; i < 32; ++i) {
    int e = base + i * 512 + t;
    if (e < NE) {
      int d = dst[e];
      int b = d >> 6;
      int r = atomicAdd(&bcnt[b], 1);
      int2 m;
      m.x = src[e] | ((d & 63) << 24);
      m.y = __float_as_int(norm[e]);
      bufA[bbase[b] + r] = m;
    }
  }
}

// ---------------------------------------------------------------------------
// Per-bucket counting sort by local node.  (proven R5)
__global__ __launch_bounds__(256) void sort_kernel(
    const int2* __restrict__ bufA, const int* __restrict__ bstart,
    int2* __restrict__ bufB, int* __restrict__ row_ptr) {
  __shared__ int lcnt[64];
  __shared__ int lbase[64];
  const int b = blockIdx.x;
  const int t = threadIdx.x;
  const int beg = bstart[b];
  const int end = bstart[b + 1];
  if (t < 64) lcnt[t] = 0;
  __syncthreads();
  for (int e = beg + t; e < end; e += 256) {
    int2 m = bufA[e];
    atomicAdd(&lcnt[(m.x >> 24) & 63], 1);
  }
  __syncthreads();
  if (t < 64) {
    int v = lcnt[t];
    int inc = v;
#pragma unroll
    for (int off = 1; off < 64; off <<= 1) {
      int x = __shfl_up(inc, off, 64);
      if (t >= off) inc += x;
    }
    int ex = inc - v;
    lbase[t] = ex;
    int n = (b << 6) + t;
    if (n < NN) row_ptr[n] = beg + ex;
    lcnt[t] = 0;
  }
  __syncthreads();
  for (int e = beg + t; e < end; e += 256) {
    int2 m = bufA[e];
    int nl = (m.x >> 24) & 63;
    int r = atomicAdd(&lcnt[nl], 1);
    int2 o;
    o.x = m.x & 0xFFFFFF;
    o.y = m.y;
    bufB[beg + lbase[nl] + r] = o;
  }
}

// ---------------------------------------------------------------------------
// Pull (R7): one wave per node. 16 lanes per edge, dwordx4 gather:
// one VMEM instr = 4 edges' full 256B bf16 rows, perfectly coalesced.
// lane = g*16 + s; group g handles edges e0+g, e0+4+g; lane owns channels
// s*8..s*8+7. Clamped edges are neutralized via nr=0 (cndmask, no branch).
// Cross-group partials folded with shfl_xor(16)+shfl_xor(32) per node.
__global__ __launch_bounds__(256) void pull_kernel(
    const unsigned short* __restrict__ gb, const int* __restrict__ row_ptr,
    const int2* __restrict__ bufB, const float* __restrict__ bias,
    float* __restrict__ out) {
  const int n = blockIdx.x * 4 + (threadIdx.x >> 6);
  if (n >= NN) return;
  const int lane = threadIdx.x & 63;
  const int s = lane & 15;   // sublane: channels s*8 .. s*8+7
  const int g = lane >> 4;   // edge group
  const int beg = row_ptr[n];
  const int end = row_ptr[n + 1];

  f32x2 accA[4], accB[4];
#pragma unroll
  for (int k = 0; k < 4; ++k) {
    accA[k] = (f32x2){0.f, 0.f};
    accB[k] = (f32x2){0.f, 0.f};
  }

  const unsigned short* gbs = gb + (s << 3);  // + s*8 elements (16B aligned)

  for (int e0 = beg; e0 < end; e0 += 8) {
    const int eA = e0 + g;
    const int eB = e0 + 4 + g;
    const int2 mA = bufB[min(eA, end - 1)];
    const int2 mB = bufB[min(eB, end - 1)];
    const uint4 qA = *(const uint4*)(gbs + ((long)mA.x << 7));
    const uint4 qB = *(const uint4*)(gbs + ((long)mB.x << 7));
    const float nrA = (eA < end) ? __int_as_float(mA.y) : 0.f;
    const float nrB = (eB < end) ? __int_as_float(mB.y) : 0.f;
    const f32x2 vA = {nrA, nrA};
    const f32x2 vB = {nrB, nrB};
    const unsigned qa[4] = {qA.x, qA.y, qA.z, qA.w};
    const unsigned qb[4] = {qB.x, qB.y, qB.z, qB.w};
#pragma unroll
    for (int k = 0; k < 4; ++k) {
      f32x2 p;
      p.x = __uint_as_float(qa[k] << 16);
      p.y = __uint_as_float(qa[k] & 0xFFFF0000u);
      accA[k] = __builtin_elementwise_fma(vA, p, accA[k]);
    }
#pragma unroll
    for (int k = 0; k < 4; ++k) {
      f32x2 p;
      p.x = __uint_as_float(qb[k] << 16);
      p.y = __uint_as_float(qb[k] & 0xFFFF0000u);
      accB[k] = __builtin_elementwise_fma(vB, p, accB[k]);
    }
  }

  float a[8];
#pragma unroll
  for (int k = 0; k < 4; ++k) {
    a[2 * k]     = accA[k].x + accB[k].x;
    a[2 * k + 1] = accA[k].y + accB[k].y;
  }
  // fold group partials: lanes {s, s+16, s+32, s+48} -> all hold full sum
#pragma unroll
  for (int k = 0; k < 8; ++k) {
    a[k] += __shfl_xor(a[k], 16, 64);
    a[k] += __shfl_xor(a[k], 32, 64);
  }
  // groups 0,1 write the two float4 halves of this sublane's 8 channels
  if (g < 2) {
    const bool hi = (g == 1);
    const float r0 = hi ? a[4] : a[0];
    const float r1 = hi ? a[5] : a[1];
    const float r2 = hi ? a[6] : a[2];
    const float r3 = hi ? a[7] : a[3];
    const int cb = (s << 3) + (g << 2);
    const float4 b4 = *(const float4*)(bias + cb);
    float4 r;
    r.x = r0 + b4.x;
    r.y = r1 + b4.y;
    r.z = r2 + b4.z;
    r.w = r3 + b4.w;
    *(float4*)(out + (long)n * D + cb) = r;
  }
}

// ---------------------------------------------------------------------------
// Fallback (ws too small): R1 path.
__global__ __launch_bounds__(256) void gemm_f32_kernel(
    const float* __restrict__ f, const float* __restrict__ w,
    float* __restrict__ g) {
  __shared__ float wlds[D * D];
  const int t = threadIdx.x;
  for (int i = t; i < D * D; i += 256) {
    int c = i >> 7, k = i & 127;
    wlds[(c << 7) + (k ^ (c & 31))] = w[i];
  }
  __syncthreads();
  const int c = t & 127;
  const int cx = c & 31;
  const int cbase = c << 7;
  const int jbase = __builtin_amdgcn_readfirstlane((t >> 7) << 3);
  const long nb = (long)blockIdx.x * 16 + jbase;
  const float* __restrict__ frow = f + nb * D;
  float acc[8] = {0.f, 0.f, 0.f, 0.f, 0.f, 0.f, 0.f, 0.f};
#pragma unroll 4
  for (int k = 0; k < D; ++k) {
    float wv = wlds[cbase + (k ^ cx)];
#pragma unroll
    for (int j = 0; j < 8; ++j) acc[j] += frow[j * D + k] * wv;
  }
#pragma unroll
  for (int j = 0; j < 8; ++j) g[(nb + j) * D + c] = acc[j];
}

__global__ __launch_bounds__(256) void init_kernel(
    const float* __restrict__ bias, float4* __restrict__ out) {
  const int i = blockIdx.x * 256 + threadIdx.x;
  const float4* b4 = (const float4*)bias;
  out[i] = b4[i & 31];
}

__global__ __launch_bounds__(256) void scatter_kernel(
    const float* __restrict__ g, const float* __restrict__ norm,
    const int* __restrict__ src, const int* __restrict__ dst,
    float* __restrict__ out) {
  const long tid = (long)blockIdx.x * 256 + threadIdx.x;
  const int e = (int)(tid >> 5);
  if (e >= NE) return;
  const int ch = (int)(tid & 31) << 2;
  const int s = src[e];
  const int d = dst[e];
  const float nr = norm[e];
  const float4 gv = *(const float4*)(g + (long)s * D + ch);
  float* op = out + (long)d * D + ch;
  unsafeAtomicAdd(op + 0, nr * gv.x);
  unsafeAtomicAdd(op + 1, nr * gv.y);
  unsafeAtomicAdd(op + 2, nr * gv.z);
  unsafeAtomicAdd(op + 3, nr * gv.w);
}

// ---------------------------------------------------------------------------
extern "C" void kernel_launch(void* const* d_in, const int* in_sizes, int n_in,
                              void* d_out, int out_size, void* d_ws,
                              size_t ws_size, hipStream_t stream) {
  const float* features = (const float*)d_in[0];
  const float* norm     = (const float*)d_in[1];
  const int*   src      = (const int*)d_in[2];
  const int*   dst      = (const int*)d_in[3];
  const float* weight   = (const float*)d_in[4];
  const float* bias     = (const float*)d_in[5];
  float* out = (float*)d_out;

  char* ws = (char*)d_ws;
  unsigned short* gb    = (unsigned short*)ws;   // [0, 25.6M)
  int2* bufA    = (int2*)(ws + 25600000);        // [25.6M, 51.2M)
  int2* bufB    = (int2*)(ws + 51200000);        // [51.2M, 76.8M)
  int*  row_ptr = (int*)(ws + 76800000);         // 400,004 B
  int*  gcnt    = (int*)(ws + 77200008);         // 6,252 B
  int*  bstart  = (int*)(ws + 77206264);         // 6,256 B
  int*  cur     = (int*)(ws + 77212524);         // 6,252 B
  unsigned short* wfrag = (unsigned short*)(ws + 77218784);  // 32,768 B
  const size_t need = 77251552;                  // ws >= 77,602,176 proven (R2)

  if (ws_size >= need) {
    hipMemsetAsync(gcnt, 0, NBKT2 * sizeof(int), stream);
    hipLaunchKernelGGL(cvtw_kernel, dim3(64), dim3(256), 0, stream,
                       weight, wfrag);
    hipLaunchKernelGGL(gemm_kernel, dim3((NTILE + 3) / 4), dim3(256), 0,
                       stream, features, wfrag, gb);
    hipLaunchKernelGGL(hist_kernel, dim3((NE + 4095) / 4096), dim3(256), 0,
                       stream, dst, gcnt);
    hipLaunchKernelGGL(scan_kernel, dim3(1), dim3(1024), 0, stream,
                       gcnt, bstart, cur, row_ptr);
    hipLaunchKernelGGL(bin_kernel, dim3((NE + 16383) / 16384), dim3(512), 0,
                       stream, src, dst, norm, cur, bufA);
    hipLaunchKernelGGL(sort_kernel, dim3(NBKT2), dim3(256), 0, stream,
                       bufA, bstart, bufB, row_ptr);
    hipLaunchKernelGGL(pull_kernel, dim3((NN + 3) / 4), dim3(256), 0, stream,
                       gb, row_ptr, bufB, bias, out);
  } else {
    float* g = (float*)ws;
    hipLaunchKernelGGL(gemm_f32_kernel, dim3(NN / 16), dim3(256), 0, stream,
                       features, weight, g);
    hipLaunchKernelGGL(init_kernel, dim3((NN * D / 4) / 256), dim3(256), 0,
                       stream, bias, (float4*)out);
    hipLaunchKernelGGL(scatter_kernel, dim3((long)NE * 32 / 256), dim3(256), 0,
                       stream, g, norm, src, dst, out);
  }
}

// Round 3
// 392.686 us; speedup vs baseline: 1.1027x; 1.0051x over previous
//
#include <hip/hip_runtime.h>

// SparseGCNConv: out = segment_sum(norm * f[src], dst, N) @ W^T + bias
// R8: pull_kernel gets (a) depth-2 software pipeline (bufB metadata prefetched
// 2 blocks ahead, gathers 1 block ahead -> no same-iteration load->load
// dependency in the steady-state loop) and (b) f16 g-matrix consumed via
// v_fma_mix_f32 op_sel (no unpack shl/and; 2 instr/dword instead of 3).
// gemm now stores its f32 accumulators as f16 (RTNE) instead of bf16 --
// same bytes, more mantissa (absmax margin improves).

#define NN    100000
#define NE    3200000
#define D     128
#define NBKT2 1563  // ceil(NN/64); bucket b = dst >> 6
#define NTILE 6250  // NN/16 node tiles (exact)

typedef __attribute__((ext_vector_type(8))) short bf16x8;
typedef __attribute__((ext_vector_type(4))) float f32x4;

static __device__ __forceinline__ unsigned short f2bf(float x) {
  unsigned u = __float_as_uint(x);
  u += 0x7FFFu + ((u >> 16) & 1u);  // RTNE
  return (unsigned short)(u >> 16);
}

// 8 channels of one gathered f16 row-slice, scaled by nr, into f32 accs.
// q.{x,y,z,w} each hold 2 f16 channels; fma_mix selects lo/hi half directly.
static __device__ __forceinline__ void fmix8(float* acc, uint4 q, float nr) {
  asm("v_fma_mix_f32 %0, %1, %2, %0 op_sel:[0,0,0] op_sel_hi:[1,0,0]"
      : "+v"(acc[0]) : "v"(q.x), "v"(nr));
  asm("v_fma_mix_f32 %0, %1, %2, %0 op_sel:[1,0,0] op_sel_hi:[1,0,0]"
      : "+v"(acc[1]) : "v"(q.x), "v"(nr));
  asm("v_fma_mix_f32 %0, %1, %2, %0 op_sel:[0,0,0] op_sel_hi:[1,0,0]"
      : "+v"(acc[2]) : "v"(q.y), "v"(nr));
  asm("v_fma_mix_f32 %0, %1, %2, %0 op_sel:[1,0,0] op_sel_hi:[1,0,0]"
      : "+v"(acc[3]) : "v"(q.y), "v"(nr));
  asm("v_fma_mix_f32 %0, %1, %2, %0 op_sel:[0,0,0] op_sel_hi:[1,0,0]"
      : "+v"(acc[4]) : "v"(q.z), "v"(nr));
  asm("v_fma_mix_f32 %0, %1, %2, %0 op_sel:[1,0,0] op_sel_hi:[1,0,0]"
      : "+v"(acc[5]) : "v"(q.z), "v"(nr));
  asm("v_fma_mix_f32 %0, %1, %2, %0 op_sel:[0,0,0] op_sel_hi:[1,0,0]"
      : "+v"(acc[6]) : "v"(q.w), "v"(nr));
  asm("v_fma_mix_f32 %0, %1, %2, %0 op_sel:[1,0,0] op_sel_hi:[1,0,0]"
      : "+v"(acc[7]) : "v"(q.w), "v"(nr));
}

// ---------------------------------------------------------------------------
// W [128][128] fp32 -> bf16 in MFMA B-fragment order:
// wfrag[((tc*4+ks)*64 + lane)*8 + j] = bf16(w[c][k])
//   where c = tc*16 + (lane&15), k = ks*32 + (lane>>4)*8 + j.
__global__ __launch_bounds__(256) void cvtw_kernel(
    const float* __restrict__ w, unsigned short* __restrict__ wfrag) {
  const int i = blockIdx.x * 256 + threadIdx.x;  // 16384 elems, 64 blocks
  const int c = i >> 7, k = i & 127;
  const int pos = ((((c >> 4) << 2) + (k >> 5)) * 64 +
                   (((k >> 3) & 3) << 4) + (c & 15)) * 8 + (k & 7);
  wfrag[pos] = f2bf(w[i]);
}

// ---------------------------------------------------------------------------
// MFMA gemm: g[n][c] = sum_k f[n][k] w[c][k], output plain row-major *f16*.
// One wave per 16-node tile, all 128 channels (8 ch-tiles x 4 k-steps).
__global__ __launch_bounds__(256) void gemm_kernel(
    const float* __restrict__ f, const unsigned short* __restrict__ wfrag,
    unsigned short* __restrict__ gh) {
  const int wv = blockIdx.x * 4 + (threadIdx.x >> 6);
  if (wv >= NTILE) return;
  const int lane = threadIdx.x & 63;
  const int mrow = lane & 15;
  const int q = lane >> 4;
  const long node = (long)wv * 16 + mrow;
  const float* fr = f + node * D + q * 8;

  bf16x8 a[4];
#pragma unroll
  for (int ks = 0; ks < 4; ++ks) {
    const float4 lo = *(const float4*)(fr + ks * 32);
    const float4 hi = *(const float4*)(fr + ks * 32 + 4);
    union { bf16x8 v; unsigned short u[8]; } pa;
    pa.u[0] = f2bf(lo.x); pa.u[1] = f2bf(lo.y);
    pa.u[2] = f2bf(lo.z); pa.u[3] = f2bf(lo.w);
    pa.u[4] = f2bf(hi.x); pa.u[5] = f2bf(hi.y);
    pa.u[6] = f2bf(hi.z); pa.u[7] = f2bf(hi.w);
    a[ks] = pa.v;
  }

  const long nbase = (long)wv * 16 + (q << 2);
#pragma unroll
  for (int tc = 0; tc < 8; ++tc) {
    f32x4 acc = {0.f, 0.f, 0.f, 0.f};
#pragma unroll
    for (int ks = 0; ks < 4; ++ks) {
      const bf16x8 b =
          *(const bf16x8*)(wfrag + (((tc << 2) + ks) * 64 + lane) * 8);
      acc = __builtin_amdgcn_mfma_f32_16x16x32_bf16(a[ks], b, acc, 0, 0, 0);
    }
    const int c = (tc << 4) + mrow;
#pragma unroll
    for (int r = 0; r < 4; ++r) {
      union { _Float16 h; unsigned short u; } cv;
      cv.h = (_Float16)acc[r];  // v_cvt_f16_f32, RTNE
      gh[(nbase + r) * D + c] = cv.u;
    }
  }
}

// ---------------------------------------------------------------------------
// Bucket histogram (1563 counters), LDS-aggregated int atomics.  (proven R5)
__global__ __launch_bounds__(256) void hist_kernel(const int* __restrict__ dst,
                                                   int* __restrict__ gcnt) {
  __shared__ int h[NBKT2];
  const int t = threadIdx.x;
  for (int b = t; b < NBKT2; b += 256) h[b] = 0;
  __syncthreads();
  const int base = blockIdx.x * 4096;
#pragma unroll
  for (int i = 0; i < 16; ++i) {
    int e = base + i * 256 + t;
    if (e < NE) atomicAdd(&h[dst[e] >> 6], 1);
  }
  __syncthreads();
  for (int b = t; b < NBKT2; b += 256)
    if (h[b]) atomicAdd(&gcnt[b], h[b]);
}

// Exclusive scan of 1563 counts.  (proven R5)
__global__ __launch_bounds__(1024) void scan_kernel(const int* __restrict__ gcnt,
                                                    int* __restrict__ bstart,
                                                    int* __restrict__ cur,
                                                    int* __restrict__ row_ptr) {
  __shared__ int s[2048];
  const int t = threadIdx.x;
  s[t] = (t < NBKT2) ? gcnt[t] : 0;
  s[t + 1024] = (t + 1024 < NBKT2) ? gcnt[t + 1024] : 0;
  __syncthreads();
  if (t < 64) {
    int part = 0;
#pragma unroll
    for (int i = 0; i < 32; ++i) part += s[(t << 5) + i];
    int inc = part;
#pragma unroll
    for (int off = 1; off < 64; off <<= 1) {
      int x = __shfl_up(inc, off, 64);
      if (t >= off) inc += x;
    }
    int run = inc - part;
#pragma unroll
    for (int i = 0; i < 32; ++i) {
      int idx = (t << 5) + i;
      int v = s[idx];
      s[idx] = run;
      run += v;
    }
  }
  __syncthreads();
  if (t < NBKT2) { bstart[t] = s[t]; cur[t] = s[t]; }
  if (t + 1024 < NBKT2) { bstart[t + 1024] = s[t + 1024]; cur[t + 1024] = s[t + 1024]; }
  if (t == 0) { bstart[NBKT2] = NE; row_ptr[NN] = NE; }
}

// ---------------------------------------------------------------------------
// Bin edges into buckets (dense runs).  (proven R5)
__global__ __launch_bounds__(512) void bin_kernel(
    const int* __restrict__ src, const int* __restrict__ dst,
    const float* __restrict__ norm, int* __restrict__ cur,
    int2* __restrict__ bufA) {
  __shared__ int bcnt[NBKT2];
  __shared__ int bbase[NBKT2];
  const int t = threadIdx.x;
  for (int b = t; b < NBKT2; b += 512) bcnt[b] = 0;
  __syncthreads();
  const int base = blockIdx.x * 16384;
#pragma unroll
  for (int i = 0; i < 32; ++i) {
    int e = base + i * 512 + t;
    if (e < NE) atomicAdd(&bcnt[dst[e] >> 6], 1);
  }
  __syncthreads();
  for (int b = t; b < NBKT2; b += 512) {
    int c = bcnt[b];
    if (c) bbase[b] = atomicAdd(&cur[b], c);
    bcnt[b] = 0;  // reuse as rank
  }
  __syncthreads();
#pragma unroll
  for (int i = 0; i < 32; ++i) {
    int e = base + i * 512 + t;
    if (e < NE) {
      int d = dst[e];
      int b = d >> 6;
      int r = atomicAdd(&bcnt[b], 1);
      int2 m;
      m.x = src[e] | ((d & 63) << 24);
      m.y = __float_as_int(norm[e]);
      bufA[bbase[b] + r] = m;
    }
  }
}

// ---------------------------------------------------------------------------
// Per-bucket counting sort by local node.  (proven R5)
__global__ __launch_bounds__(256) void sort_kernel(
    const int2* __restrict__ bufA, const int* __restrict__ bstart,
    int2* __restrict__ bufB, int* __restrict__ row_ptr) {
  __shared__ int lcnt[64];
  __shared__ int lbase[64];
  const int b = blockIdx.x;
  const int t = threadIdx.x;
  const int beg = bstart[b];
  const int end = bstart[b + 1];
  if (t < 64) lcnt[t] = 0;
  __syncthreads();
  for (int e = beg + t; e < end; e += 256) {
    int2 m = bufA[e];
    atomicAdd(&lcnt[(m.x >> 24) & 63], 1);
  }
  __syncthreads();
  if (t < 64) {
    int v = lcnt[t];
    int inc = v;
#pragma unroll
    for (int off = 1; off < 64; off <<= 1) {
      int x = __shfl_up(inc, off, 64);
      if (t >= off) inc += x;
    }
    int ex = inc - v;
    lbase[t] = ex;
    int n = (b << 6) + t;
    if (n < NN) row_ptr[n] = beg + ex;
    lcnt[t] = 0;
  }
  __syncthreads();
  for (int e = beg + t; e < end; e += 256) {
    int2 m = bufA[e];
    int nl = (m.x >> 24) & 63;
    int r = atomicAdd(&lcnt[nl], 1);
    int2 o;
    o.x = m.x & 0xFFFFFF;
    o.y = m.y;
    bufB[beg + lbase[nl] + r] = o;
  }
}

// ---------------------------------------------------------------------------
// Pull (R8): one wave per node; 16 lanes per edge; dwordx4 f16 gathers.
// Depth-2 pipeline: in the steady-state loop, bufB metadata for block t+2 and
// gathers for block t+1 are issued before consuming block t -- no load in the
// loop depends on a load issued in the same iteration. Full blocks are
// consumed unguarded; only the final (partial) block uses nr=0 guards.
// fma_mix consumes f16 halves directly (no unpack).
__global__ __launch_bounds__(256) void pull_kernel(
    const unsigned short* __restrict__ gh, const int* __restrict__ row_ptr,
    const int2* __restrict__ bufB, const float* __restrict__ bias,
    float* __restrict__ out) {
  const int n = blockIdx.x * 4 + (threadIdx.x >> 6);
  if (n >= NN) return;
  const int lane = threadIdx.x & 63;
  const int s = lane & 15;   // sublane: channels s*8 .. s*8+7
  const int g = lane >> 4;   // edge group
  const int beg = row_ptr[n];
  const int end = row_ptr[n + 1];

  float acc[8] = {0.f, 0.f, 0.f, 0.f, 0.f, 0.f, 0.f, 0.f};

  if (beg < end) {
    const char* gbase = (const char*)gh;
    const unsigned soff = (unsigned)(s << 4);  // byte offset within row
    const int last = end - 1;
    int e0 = beg;
    // prologue: block 0 metadata + gathers, block 1 metadata
    int2 mA0 = bufB[min(e0 + g, last)];
    int2 mB0 = bufB[min(e0 + 4 + g, last)];
    uint4 qA0 = *(const uint4*)(gbase + (((unsigned)mA0.x << 8) + soff));
    uint4 qB0 = *(const uint4*)(gbase + (((unsigned)mB0.x << 8) + soff));
    int2 mA1 = bufB[min(e0 + 8 + g, last)];
    int2 mB1 = bufB[min(e0 + 12 + g, last)];
    while (e0 + 8 < end) {
      // issue block t+2 metadata
      const int2 mA2 = bufB[min(e0 + 16 + g, last)];
      const int2 mB2 = bufB[min(e0 + 20 + g, last)];
      // issue block t+1 gathers (metadata loaded last iteration)
      const uint4 qA1 =
          *(const uint4*)(gbase + (((unsigned)mA1.x << 8) + soff));
      const uint4 qB1 =
          *(const uint4*)(gbase + (((unsigned)mB1.x << 8) + soff));
      // consume block t (fully valid: e0+8 <= end-1 here)
      fmix8(acc, qA0, __int_as_float(mA0.y));
      fmix8(acc, qB0, __int_as_float(mB0.y));
      mA0 = mA1; mB0 = mB1;
      mA1 = mA2; mB1 = mB2;
      qA0 = qA1; qB0 = qB1;
      e0 += 8;
    }
    // epilogue: final (possibly partial) block, guarded via nr=0
    const float nrA = (e0 + g < end) ? __int_as_float(mA0.y) : 0.f;
    const float nrB = (e0 + 4 + g < end) ? __int_as_float(mB0.y) : 0.f;
    fmix8(acc, qA0, nrA);
    fmix8(acc, qB0, nrB);
  }

  // fold group partials: lanes {s, s+16, s+32, s+48} -> all hold full sum
#pragma unroll
  for (int k = 0; k < 8; ++k) {
    acc[k] += __shfl_xor(acc[k], 16, 64);
    acc[k] += __shfl_xor(acc[k], 32, 64);
  }
  // groups 0,1 write the two float4 halves of this sublane's 8 channels
  if (g < 2) {
    const bool hi = (g == 1);
    const float r0 = hi ? acc[4] : acc[0];
    const float r1 = hi ? acc[5] : acc[1];
    const float r2 = hi ? acc[6] : acc[2];
    const float r3 = hi ? acc[7] : acc[3];
    const int cb = (s << 3) + (g << 2);
    const float4 b4 = *(const float4*)(bias + cb);
    float4 r;
    r.x = r0 + b4.x;
    r.y = r1 + b4.y;
    r.z = r2 + b4.z;
    r.w = r3 + b4.w;
    *(float4*)(out + (long)n * D + cb) = r;
  }
}

// ---------------------------------------------------------------------------
// Fallback (ws too small): R1 path.
__global__ __launch_bounds__(256) void gemm_f32_kernel(
    const float* __restrict__ f, const float* __restrict__ w,
    float* __restrict__ g) {
  __shared__ float wlds[D * D];
  const int t = threadIdx.x;
  for (int i = t; i < D * D; i += 256) {
    int c = i >> 7, k = i & 127;
    wlds[(c << 7) + (k ^ (c & 31))] = w[i];
  }
  __syncthreads();
  const int c = t & 127;
  const int cx = c & 31;
  const int cbase = c << 7;
  const int jbase = __builtin_amdgcn_readfirstlane((t >> 7) << 3);
  const long nb = (long)blockIdx.x * 16 + jbase;
  const float* __restrict__ frow = f + nb * D;
  float acc[8] = {0.f, 0.f, 0.f, 0.f, 0.f, 0.f, 0.f, 0.f};
#pragma unroll 4
  for (int k = 0; k < D; ++k) {
    float wv = wlds[cbase + (k ^ cx)];
#pragma unroll
    for (int j = 0; j < 8; ++j) acc[j] += frow[j * D + k] * wv;
  }
#pragma unroll
  for (int j = 0; j < 8; ++j) g[(nb + j) * D + c] = acc[j];
}

__global__ __launch_bounds__(256) void init_kernel(
    const float* __restrict__ bias, float4* __restrict__ out) {
  const int i = blockIdx.x * 256 + threadIdx.x;
  const float4* b4 = (const float4*)bias;
  out[i] = b4[i & 31];
}

__global__ __launch_bounds__(256) void scatter_kernel(
    const float* __restrict__ g, const float* __restrict__ norm,
    const int* __restrict__ src, const int* __restrict__ dst,
    float* __restrict__ out) {
  const long tid = (long)blockIdx.x * 256 + threadIdx.x;
  const int e = (int)(tid >> 5);
  if (e >= NE) return;
  const int ch = (int)(tid & 31) << 2;
  const int s = src[e];
  const int d = dst[e];
  const float nr = norm[e];
  const float4 gv = *(const float4*)(g + (long)s * D + ch);
  float* op = out + (long)d * D + ch;
  unsafeAtomicAdd(op + 0, nr * gv.x);
  unsafeAtomicAdd(op + 1, nr * gv.y);
  unsafeAtomicAdd(op + 2, nr * gv.z);
  unsafeAtomicAdd(op + 3, nr * gv.w);
}

// ---------------------------------------------------------------------------
extern "C" void kernel_launch(void* const* d_in, const int* in_sizes, int n_in,
                              void* d_out, int out_size, void* d_ws,
                              size_t ws_size, hipStream_t stream) {
  const float* features = (const float*)d_in[0];
  const float* norm     = (const float*)d_in[1];
  const int*   src      = (const int*)d_in[2];
  const int*   dst      = (const int*)d_in[3];
  const float* weight   = (const float*)d_in[4];
  const float* bias     = (const float*)d_in[5];
  float* out = (float*)d_out;

  char* ws = (char*)d_ws;
  unsigned short* gh    = (unsigned short*)ws;   // [0, 25.6M)  f16 g-matrix
  int2* bufA    = (int2*)(ws + 25600000);        // [25.6M, 51.2M)
  int2* bufB    = (int2*)(ws + 51200000);        // [51.2M, 76.8M)
  int*  row_ptr = (int*)(ws + 76800000);         // 400,004 B
  int*  gcnt    = (int*)(ws + 77200008);         // 6,252 B
  int*  bstart  = (int*)(ws + 77206264);         // 6,256 B
  int*  cur     = (int*)(ws + 77212524);         // 6,252 B
  unsigned short* wfrag = (unsigned short*)(ws + 77218784);  // 32,768 B
  const size_t need = 77251552;                  // ws >= 77,602,176 proven (R2)

  if (ws_size >= need) {
    hipMemsetAsync(gcnt, 0, NBKT2 * sizeof(int), stream);
    hipLaunchKernelGGL(cvtw_kernel, dim3(64), dim3(256), 0, stream,
                       weight, wfrag);
    hipLaunchKernelGGL(gemm_kernel, dim3((NTILE + 3) / 4), dim3(256), 0,
                       stream, features, wfrag, gh);
    hipLaunchKernelGGL(hist_kernel, dim3((NE + 4095) / 4096), dim3(256), 0,
                       stream, dst, gcnt);
    hipLaunchKernelGGL(scan_kernel, dim3(1), dim3(1024), 0, stream,
                       gcnt, bstart, cur, row_ptr);
    hipLaunchKernelGGL(bin_kernel, dim3((NE + 16383) / 16384), dim3(512), 0,
                       stream, src, dst, norm, cur, bufA);
    hipLaunchKernelGGL(sort_kernel, dim3(NBKT2), dim3(256), 0, stream,
                       bufA, bstart, bufB, row_ptr);
    hipLaunchKernelGGL(pull_kernel, dim3((NN + 3) / 4), dim3(256), 0, stream,
                       gh, row_ptr, bufB, bias, out);
  } else {
    float* g = (float*)ws;
    hipLaunchKernelGGL(gemm_f32_kernel, dim3(NN / 16), dim3(256), 0, stream,
                       features, weight, g);
    hipLaunchKernelGGL(init_kernel, dim3((NN * D / 4) / 256), dim3(256), 0,
                       stream, bias, (float4*)out);
    hipLaunchKernelGGL(scatter_kernel, dim3((long)NE * 32 / 256), dim3(256), 0,
                       stream, g, norm, src, dst, out);
  }
}